// Round 9
// baseline (256.052 us; speedup 1.0000x reference)
//
#include <hip/hip_runtime.h>
#include <math.h>

typedef unsigned short ushort_t;
typedef __attribute__((ext_vector_type(4))) float floatx4;
typedef __attribute__((ext_vector_type(8))) short shortx8;
typedef __attribute__((ext_vector_type(8))) unsigned short ushortx8;

__device__ __forceinline__ float bf2f(ushort_t h) {
    union { unsigned u; float f; } x; x.u = ((unsigned)h) << 16; return x.f;
}
__device__ __forceinline__ ushort_t f2bf(float f) {
    union { float f; unsigned u; } x; x.f = f;
    unsigned r = x.u + 0x7fffu + ((x.u >> 16) & 1u);
    return (ushort_t)(r >> 16);
}
__device__ __forceinline__ float rdIn(const void* p, size_t i, int f32) {
    return f32 ? ((const float*)p)[i] : bf2f(((const ushort_t*)p)[i]);
}
// async global->LDS DMA, 16 B per lane (dest must be wave-uniform base + lane*16)
__device__ __forceinline__ void gload16(const ushort_t* g, ushort_t* l) {
    __builtin_amdgcn_global_load_lds(
        (const __attribute__((address_space(1))) unsigned int*)g,
        (__attribute__((address_space(3))) unsigned int*)l, 16, 0, 0);
}
// branch-free GELU: erf via Abramowitz-Stegun 7.1.26 (|erf err| <= 1.5e-7)
__device__ __forceinline__ float gelu_f(float v) {
    float z = fabsf(v) * 0.70710678118654752f;
    float t = __builtin_amdgcn_rcpf(1.0f + 0.3275911f * z);
    float p = 1.061405429f;
    p = p * t - 1.453152027f;
    p = p * t + 1.421413741f;
    p = p * t - 0.284496736f;
    p = p * t + 0.254829592f;
    p = p * t;
    float er = 1.0f - p * __expf(-z * z);
    er = copysignf(er, v);
    return 0.5f * v * (1.0f + er);
}

// ---------------- unified pre-stage: detect + 3 transposes + prep -----------
// grid 4864 x 256thr:
//   [0,768)     transpose Wq/Wk/Wv [512,512] -> Wqt[z][512][512]
//   [768,1792)  transpose W1 [512,2048]      -> W1t[2048][512]
//   [1792,2816) transpose W2 [2048,512]      -> W2P panel-major [64][512][32]
//   [2816,4864) prep x [2,4095,512] raw      -> Xp [2,4096,512] bf16
// dtype detect inlined per-block; block 0 publishes flg for downstream.
__global__ __launch_bounds__(256) void pre_kernel(
    const void* __restrict__ x, const void* __restrict__ Wq,
    const void* __restrict__ Wk, const void* __restrict__ Wv,
    const void* __restrict__ W1, const void* __restrict__ W2,
    ushort_t* __restrict__ Xp, ushort_t* __restrict__ Wqt,
    ushort_t* __restrict__ W1t, ushort_t* __restrict__ W2t,
    int* __restrict__ flg) {
    const int t = threadIdx.x;
    const int b = blockIdx.x;

    __shared__ int cnt;
    __shared__ ushort_t tile[32][33];
    if (t == 0) cnt = 0;
    __syncthreads();
    {
        ushort_t v = ((const ushort_t*)x)[t];
        int e = (v >> 7) & 0xff;
        int ok = (e >= 100 && e <= 150) || (v == 0);
        atomicAdd(&cnt, ok);
    }
    __syncthreads();
    const int f32 = (cnt >= 240) ? 0 : 1;
    if (b == 0 && t == 0) flg[0] = f32;

    if (b < 2816) {
        const void* in;
        ushort_t* out;
        int R, C, panel, bx, by, z = 0;
        if (b < 768) {
            z = b >> 8;
            int inner = b & 255;
            in = (z == 0) ? Wq : (z == 1) ? Wk : Wv;
            out = Wqt; R = 512; C = 512; panel = 0;
            bx = inner & 15; by = inner >> 4;
        } else if (b < 1792) {
            int inner = b - 768;
            in = W1; out = W1t; R = 512; C = 2048; panel = 0;
            bx = inner & 63; by = inner >> 6;
        } else {
            int inner = b - 1792;
            in = W2; out = W2t; R = 2048; C = 512; panel = 1;
            bx = inner & 15; by = inner >> 4;
        }
        int c0 = bx * 32, r0 = by * 32;
        int tx = t & 31, ty = t >> 5;
#pragma unroll
        for (int i = 0; i < 4; i++) {
            size_t idx = (size_t)(r0 + ty + 8 * i) * C + c0 + tx;
            tile[ty + 8 * i][tx] = f32 ? f2bf(((const float*)in)[idx])
                                       : ((const ushort_t*)in)[idx];
        }
        __syncthreads();
#pragma unroll
        for (int i = 0; i < 4; i++) {
            if (panel)
                out[((size_t)(r0 >> 5) * C + (c0 + ty + 8 * i)) * 32 + tx] =
                    tile[tx][ty + 8 * i];
            else
                out[(size_t)z * R * C + (size_t)(c0 + ty + 8 * i) * R + r0 + tx] =
                    tile[tx][ty + 8 * i];
        }
    } else {
        int i = (b - 2816) * 256 + t;
        int e = i * 8;
        int s = (e >> 9) & 4095;
        int bb = e >> 21;
        ushortx8 val = {0, 0, 0, 0, 0, 0, 0, 0};
        if (s < 4095) {
            size_t src = ((size_t)(bb * 4095 + s) << 9) + (e & 511);
            if (f32) {
                const float* p = (const float*)x + src;
                floatx4 a = *(const floatx4*)p;
                floatx4 c = *(const floatx4*)(p + 4);
                val[0] = f2bf(a[0]); val[1] = f2bf(a[1]); val[2] = f2bf(a[2]); val[3] = f2bf(a[3]);
                val[4] = f2bf(c[0]); val[5] = f2bf(c[1]); val[6] = f2bf(c[2]); val[7] = f2bf(c[3]);
            } else {
                val = *(const ushortx8*)((const ushort_t*)x + src);
            }
        }
        *(ushortx8*)&Xp[e] = val;
    }
}

// ---------------- 128x128 GEMM for K=512 (QKV, MLP1) ------------------------
// The round-7 splitk schedule minus the split: 256 thr = 4 waves (2x2 of
// 64x64, acc[4][4]), BK=32 -> KT=16 (2x deeper than the 8p kernel), 4-deep
// LDS ring at 64 KiB -> 2 blocks/CU (second resident block hides the
// barrier-lockstep that capped the 1-block/CU 8p kernels), counted vmcnt(8),
// one s_barrier/step, setprio, chunk-XOR swizzle (src (t&3)^((t>>3)&3),
// read quad^((l16>>1)&3); (t>>3)&3 == (row>>1)&3 == (l16>>1)&3 mod 4).
// Grid 1D multiple of 8; 64 M-tiles x (N/128) N-tiles, XCD-chunk swizzled.
// EPI 3: QKV merged out + bias (+scale on Q); tile never crosses a 512
//        boundary (128 | 512) so idx = n0>>9 is block-uniform.
// EPI 1: gelu(v+bias), written PANEL-MAJOR Gs2[N/32][M][32] (MLP2 contract).
template<int EPI>
__global__ __launch_bounds__(256, 2) void gemm128_kernel(
    const ushort_t* __restrict__ A, const ushort_t* __restrict__ Bt,
    const void* __restrict__ bias0, const void* __restrict__ bias1,
    const void* __restrict__ bias2, void* outp,
    int K, float scale, const int* __restrict__ flag) {
    const int f32 = flag[0];
    __shared__ __align__(16) ushort_t SH[32768];   // 64 KiB
    const int t = threadIdx.x;
    const int lane = t & 63, wave = t >> 6;
    const int wr = (wave >> 1) & 1, wc = wave & 1;
    const int l16 = lane & 15, quad = lane >> 4;
    const int pc16 = (quad ^ ((l16 >> 1) & 3)) * 8;

    // XCD chunk swizzle (grid % 8 == 0), then mt = sb&63, nt = sb>>6
    const int nwg = gridDim.x;
    const int bid = blockIdx.x;
    const int cpx = nwg >> 3;
    const int sb = (bid & 7) * cpx + (bid >> 3);
    const int m0 = (sb & 63) * 128, n0 = (sb >> 6) * 128;

    const int sr = t >> 2;                           // 0..63
    const int sc8 = ((t & 3) ^ ((t >> 3) & 3)) * 8;  // pre-swizzled src chunk
    const ushort_t* Ag = A + (size_t)(m0 + sr) * K + sc8;
    const ushort_t* Bg = Bt + (size_t)(n0 + sr) * K + sc8;
    ushort_t* Sd = SH + t * 8;

    // LDS: A[buf] = buf*4096 (plane 128x32 ushorts), B[buf] = 16384 + buf*4096
    auto STAGE = [&](int kt) {
        const int b = kt & 3;
        gload16(Ag + kt * 32,                  Sd + b * 4096);
        gload16(Ag + (size_t)64 * K + kt * 32, Sd + b * 4096 + 2048);
        gload16(Bg + kt * 32,                  Sd + 16384 + b * 4096);
        gload16(Bg + (size_t)64 * K + kt * 32, Sd + 16384 + b * 4096 + 2048);
    };

    floatx4 acc[4][4];
#pragma unroll
    for (int i = 0; i < 4; i++)
#pragma unroll
        for (int j = 0; j < 4; j++)
#pragma unroll
            for (int r = 0; r < 4; r++) acc[i][j][r] = 0.f;

    const int KT = K / 32;   // 16
    STAGE(0); STAGE(1); STAGE(2);

    for (int kt = 0; kt < KT; kt++) {
        if (kt + 2 < KT)      asm volatile("s_waitcnt vmcnt(8)" ::: "memory");
        else if (kt + 1 < KT) asm volatile("s_waitcnt vmcnt(4)" ::: "memory");
        else                  asm volatile("s_waitcnt vmcnt(0)" ::: "memory");
        __builtin_amdgcn_s_barrier();
        asm volatile("" ::: "memory");
        if (kt + 3 < KT) STAGE(kt + 3);   // overwrites buf[(kt-1)&3]: reads done

        const int ab = (kt & 3) * 4096;
        shortx8 af[4], bfr[4];
#pragma unroll
        for (int nf = 0; nf < 4; nf++)
            bfr[nf] = *(const shortx8*)&SH[16384 + ab + (wc * 64 + nf * 16 + l16) * 32 + pc16];
#pragma unroll
        for (int mf = 0; mf < 4; mf++)
            af[mf] = *(const shortx8*)&SH[ab + (wr * 64 + mf * 16 + l16) * 32 + pc16];

        __builtin_amdgcn_s_setprio(1);
#pragma unroll
        for (int mf = 0; mf < 4; mf++)
#pragma unroll
            for (int nf = 0; nf < 4; nf++)
                acc[mf][nf] = __builtin_amdgcn_mfma_f32_16x16x32_bf16(
                    af[mf], bfr[nf], acc[mf][nf], 0, 0, 0);
        __builtin_amdgcn_s_setprio(0);
    }

    // ---------------- epilogue ----------------------------------------------
    float bias[4];
    float scl = 1.0f;
    if (EPI == 3) {
        int idx = n0 >> 9;
        const void* bp = (idx == 0) ? bias0 : (idx == 1) ? bias1 : bias2;
#pragma unroll
        for (int j = 0; j < 4; j++)
            bias[j] = rdIn(bp, (n0 & 511) + wc * 64 + j * 16 + l16, f32);
        scl = (idx == 0) ? scale : 1.0f;
    } else {
#pragma unroll
        for (int j = 0; j < 4; j++)
            bias[j] = rdIn(bias0, n0 + wc * 64 + j * 16 + l16, f32);
    }

#pragma unroll
    for (int i = 0; i < 4; i++) {
#pragma unroll
        for (int j = 0; j < 4; j++) {
#pragma unroll
            for (int r = 0; r < 4; r++) {
                int m = m0 + wr * 64 + i * 16 + quad * 4 + r;
                int n = n0 + wc * 64 + j * 16 + l16;
                float v = acc[i][j][r] + bias[j];
                if (EPI == 3) {
                    ((ushort_t*)outp)[(size_t)(n0 >> 9) * 4194304 +
                                      (size_t)m * 512 + (n & 511)] = f2bf(v * scl);
                } else {
                    v = gelu_f(v);
                    ((ushort_t*)outp)[(size_t)(n >> 5) * 262144 +
                                      (size_t)m * 32 + (n & 31)] = f2bf(v);
                }
            }
        }
    }
}

// ---------------- split-K 128x128 GEMM for MLP2, dense panel staging --------
// grid 256 = 64 mt x 4 nt, 8 waves (kh, wr, wc) w/ 64x64 subtiles, BK=32,
// KT=32, 4-deep LDS ring, counted vmcnt(8), one barrier/step, in-LDS split-K
// reduce. A = Gs2[K/32][8192][32] and B = W2P[K/32][512][32] are PANEL-MAJOR:
// each of the 4 DMAs per step reads an 8 KB fully-contiguous block.
__global__ __launch_bounds__(512, 2) void gemm_splitk_kernel(
    const ushort_t* __restrict__ A, const ushort_t* __restrict__ Bt,
    const void* __restrict__ bias0, void* outp,
    const ushort_t* __restrict__ resid, const int* __restrict__ flag) {
    const int f32 = flag[0];
    __shared__ __align__(16) ushort_t SH[65536];   // 128 KiB
    const int t = threadIdx.x;
    const int lane = t & 63, wave = t >> 6;
    const int kh = wave >> 2, wr = (wave >> 1) & 1, wc = wave & 1;
    const int l16 = lane & 15, quad = lane >> 4;
    const int pc16 = (quad ^ ((l16 >> 1) & 3)) * 8;

    // XCD-aware tile map: XCD pair shares a B panel (nt), streams 32 A panels
    const int bid = blockIdx.x;
    const int xcd = bid & 7, i5 = bid >> 3;
    const int nt = xcd >> 1;
    const int mt = (xcd & 1) * 32 + i5;
    const int m0 = mt * 128, n0 = nt * 128;

    const int sr = t >> 2;                           // 0..127
    const int sc8 = ((t & 3) ^ ((t >> 3) & 3)) * 8;  // pre-swizzled chunk
    const ushort_t* Ag = A + (size_t)(m0 + sr) * 32 + sc8;
    const ushort_t* Bg = Bt + (size_t)(n0 + sr) * 32 + sc8;
    ushort_t* Sd = SH + t * 8;

    // LDS ushort layout: A[buf][kh]: buf*8192 + kh*4096 (plane = 128x32)
    //                    B[buf][kh]: 32768 + buf*8192 + kh*4096
    // A panel stride = 8192*32 = 262144 ushorts; B = 512*32 = 16384.
    auto STAGE = [&](int kt) {
        const int b = kt & 3;
        gload16(Ag + (size_t)kt * 262144,        Sd + b * 8192);
        gload16(Ag + (size_t)(32 + kt) * 262144, Sd + b * 8192 + 4096);
        gload16(Bg + (size_t)kt * 16384,         Sd + 32768 + b * 8192);
        gload16(Bg + (size_t)(32 + kt) * 16384,  Sd + 32768 + b * 8192 + 4096);
    };

    floatx4 acc[4][4];
#pragma unroll
    for (int i = 0; i < 4; i++)
#pragma unroll
        for (int j = 0; j < 4; j++)
#pragma unroll
            for (int r = 0; r < 4; r++) acc[i][j][r] = 0.f;

    const int KT = 32;
    STAGE(0); STAGE(1); STAGE(2);

    for (int kt = 0; kt < KT; kt++) {
        if (kt + 2 < KT)      asm volatile("s_waitcnt vmcnt(8)" ::: "memory");
        else if (kt + 1 < KT) asm volatile("s_waitcnt vmcnt(4)" ::: "memory");
        else                  asm volatile("s_waitcnt vmcnt(0)" ::: "memory");
        __builtin_amdgcn_s_barrier();
        asm volatile("" ::: "memory");
        if (kt + 3 < KT) STAGE(kt + 3);   // overwrites buf[(kt-1)&3]: reads done

        const int ab = (kt & 3) * 8192 + kh * 4096;
        shortx8 af[4], bfr[4];
#pragma unroll
        for (int nf = 0; nf < 4; nf++)
            bfr[nf] = *(const shortx8*)&SH[32768 + ab + (wc * 64 + nf * 16 + l16) * 32 + pc16];
#pragma unroll
        for (int mf = 0; mf < 4; mf++)
            af[mf] = *(const shortx8*)&SH[ab + (wr * 64 + mf * 16 + l16) * 32 + pc16];

        __builtin_amdgcn_s_setprio(1);
#pragma unroll
        for (int mf = 0; mf < 4; mf++)
#pragma unroll
            for (int nf = 0; nf < 4; nf++)
                acc[mf][nf] = __builtin_amdgcn_mfma_f32_16x16x32_bf16(
                    af[mf], bfr[nf], acc[mf][nf], 0, 0, 0);
        __builtin_amdgcn_s_setprio(0);
    }

    // ---------------- in-LDS split-K reduce + epi-2 store -------------------
    __syncthreads();                       // all ds reads done before overwrite
    float* RED = (float*)SH;               // 64 KiB fp32 scratch
    if (kh == 1) {
        const int base = ((wave & 3) * 64 + lane) * 16;
#pragma unroll
        for (int i = 0; i < 4; i++)
#pragma unroll
            for (int j = 0; j < 4; j++) {
                int k2 = (i * 4 + j + l16) & 15;   // per-lane rotate: spread banks
                *(floatx4*)&RED[(base + k2) * 4] = acc[i][j];
            }
    }
    __syncthreads();
    if (kh == 0) {
        const int base = (wave * 64 + lane) * 16;
#pragma unroll
        for (int i = 0; i < 4; i++)
#pragma unroll
            for (int j = 0; j < 4; j++) {
                int k2 = (i * 4 + j + l16) & 15;
                floatx4 p = *(const floatx4*)&RED[(base + k2) * 4];
#pragma unroll
                for (int r = 0; r < 4; r++) acc[i][j][r] += p[r];
            }
#pragma unroll
        for (int i = 0; i < 4; i++) {
#pragma unroll
            for (int j = 0; j < 4; j++) {
#pragma unroll
                for (int r = 0; r < 4; r++) {
                    int m = m0 + wr * 64 + i * 16 + quad * 4 + r;
                    int n = n0 + wc * 64 + j * 16 + l16;
                    int bb = m >> 12, s = m & 4095;
                    if (s < 4095) {
                        float v = acc[i][j][r] + rdIn(bias0, n, f32) +
                                  bf2f(resid[(size_t)m * 512 + n]);
                        size_t oidx = ((size_t)bb * 4095 + s) * 512 + n;
                        if (f32) ((float*)outp)[oidx] = v;
                        else     ((ushort_t*)outp)[oidx] = f2bf(v);
                    }
                }
            }
        }
    }
}

// ---------------- MFMA windowed attention + global key ----------------------
#define ALD 344

__global__ __launch_bounds__(256) void attn_mfma_kernel(
    ushort_t* Q, const ushort_t* __restrict__ Kx, const ushort_t* __restrict__ Vx) {
    __shared__ ushort_t Pl[64][ALD];
    __shared__ ushort_t Vt[2][64][40];
    __shared__ float pgl[64];

    const int t = threadIdx.x;
    const int lane = t & 63, w = t >> 6;
    const int l16 = lane & 15, quad = lane >> 4;
    const int bid = blockIdx.x;
    const int qt = bid & 63;
    const int h = (bid >> 6) & 7;
    const int b = bid >> 9;
    const int q0 = qt * 64;
    const int jmin = q0 - 128;
    const size_t base = ((size_t)b * 4096) * 512 + (size_t)h * 64;

    const int qw = q0 + w * 16;
    const int lo = qw - 128, hi = qw + 15 + 128;

    shortx8 qf0, qf1;
    {
        const ushort_t* qp = Q + base + (size_t)(qw + l16) * 512 + quad * 8;
        qf0 = *(const shortx8*)(qp);
        qf1 = *(const shortx8*)(qp + 32);
    }

    floatx4 s[21];
#pragma unroll
    for (int i = 0; i < 21; i++)
#pragma unroll
        for (int r = 0; r < 4; r++) s[i][r] = 0.f;

#pragma unroll
    for (int tt = 0; tt < 20; tt++) {
        int jt = jmin + tt * 16;
        if (jt + 15 < lo || jt > hi) continue;
        int key = jt + l16;
        int kcl = min(max(key, 0), 4094);
        const ushort_t* kp = Kx + base + (size_t)kcl * 512 + quad * 8;
        shortx8 k0 = *(const shortx8*)(kp);
        shortx8 k1 = *(const shortx8*)(kp + 32);
        s[tt] = __builtin_amdgcn_mfma_f32_16x16x32_bf16(qf0, k0, s[tt], 0, 0, 0);
        s[tt] = __builtin_amdgcn_mfma_f32_16x16x32_bf16(qf1, k1, s[tt], 0, 0, 0);
    }
    {
        const ushort_t* kp = Kx + base + (size_t)4095 * 512 + quad * 8;
        shortx8 k0 = *(const shortx8*)(kp);
        shortx8 k1 = *(const shortx8*)(kp + 32);
        s[20] = __builtin_amdgcn_mfma_f32_16x16x32_bf16(qf0, k0, s[20], 0, 0, 0);
        s[20] = __builtin_amdgcn_mfma_f32_16x16x32_bf16(qf1, k1, s[20], 0, 0, 0);
    }

#pragma unroll
    for (int tt = 0; tt < 20; tt++) {
        int j = jmin + tt * 16 + l16;
        bool okj = (j >= 0) && (j <= 4094);
#pragma unroll
        for (int r = 0; r < 4; r++) {
            int q = qw + quad * 4 + r;
            bool ok = okj && (j - q <= 128) && (q - j <= 128);
            if (!ok) s[tt][r] = -1e30f;
        }
    }
    if (l16 != 0) {
#pragma unroll
        for (int r = 0; r < 4; r++) s[20][r] = -1e30f;
    }

    floatx4 mx = s[0];
#pragma unroll
    for (int tt = 1; tt < 21; tt++)
#pragma unroll
        for (int r = 0; r < 4; r++) mx[r] = fmaxf(mx[r], s[tt][r]);
#pragma unroll
    for (int off = 1; off < 16; off <<= 1)
#pragma unroll
        for (int r = 0; r < 4; r++) mx[r] = fmaxf(mx[r], __shfl_xor(mx[r], off, 64));

    floatx4 sum;
#pragma unroll
    for (int r = 0; r < 4; r++) sum[r] = 0.f;
#pragma unroll
    for (int tt = 0; tt < 21; tt++)
#pragma unroll
        for (int r = 0; r < 4; r++) {
            float e = __expf(s[tt][r] - mx[r]);
            s[tt][r] = e;
            sum[r] += e;
        }
#pragma unroll
    for (int off = 1; off < 16; off <<= 1)
#pragma unroll
        for (int r = 0; r < 4; r++) sum[r] += __shfl_xor(sum[r], off, 64);

    floatx4 inv;
#pragma unroll
    for (int r = 0; r < 4; r++) inv[r] = 1.f / sum[r];

#pragma unroll
    for (int tt = 0; tt < 20; tt++)
#pragma unroll
        for (int r = 0; r < 4; r++)
            Pl[w * 16 + quad * 4 + r][tt * 16 + l16] = f2bf(s[tt][r]);
    if (l16 == 0) {
#pragma unroll
        for (int r = 0; r < 4; r++) pgl[w * 16 + quad * 4 + r] = s[20][r];
    }

    floatx4 o[4];
#pragma unroll
    for (int nt = 0; nt < 4; nt++)
#pragma unroll
        for (int r = 0; r < 4; r++) o[nt][r] = 0.f;

    const int ck = t & 31, cd = t >> 5;
    ushortx8 vreg;
    {
        int row = min(max(jmin + ck, 0), 4095);
        vreg = *(const ushortx8*)&Vx[base + (size_t)row * 512 + cd * 8];
    }
    for (int c = 0; c < 10; c++) {
#pragma unroll
        for (int e = 0; e < 8; e++) Vt[c & 1][cd * 8 + e][ck] = vreg[e];
        if (c < 9) {
            int row = min(max(jmin + (c + 1) * 32 + ck, 0), 4095);
            vreg = *(const ushortx8*)&Vx[base + (size_t)row * 512 + cd * 8];
        }
        __syncthreads();
        int jc = jmin + c * 32;
        if (jc + 31 >= lo && jc <= hi) {
            shortx8 pf = *(const shortx8*)&Pl[w * 16 + l16][c * 32 + quad * 8];
#pragma unroll
            for (int nt = 0; nt < 4; nt++) {
                shortx8 vf = *(const shortx8*)&Vt[c & 1][nt * 16 + l16][quad * 8];
                o[nt] = __builtin_amdgcn_mfma_f32_16x16x32_bf16(pf, vf, o[nt], 0, 0, 0);
            }
        }
    }

#pragma unroll
    for (int nt = 0; nt < 4; nt++) {
        float vg = bf2f(Vx[base + (size_t)4095 * 512 + nt * 16 + l16]);
#pragma unroll
        for (int r = 0; r < 4; r++) {
            float pg = pgl[w * 16 + quad * 4 + r];
            float val = (o[nt][r] + pg * vg) * inv[r];
            Q[base + (size_t)(qw + quad * 4 + r) * 512 + nt * 16 + l16] = f2bf(val);
        }
    }
}

// ---------------- residual + LayerNorm, in-place on hio ---------------------
__global__ __launch_bounds__(256) void ln_kernel(
    const void* __restrict__ x, ushort_t* hio,
    const void* __restrict__ g, const void* __restrict__ bta,
    const int* __restrict__ flag) {
    const int f32 = flag[0];
    const int r = blockIdx.x;
    const int b = (r >= 4095) ? 1 : 0;
    const int s = r - b * 4095;
    const size_t xrow = (size_t)r * 512;
    const size_t hrow = ((size_t)b * 4096 + s) * 512;
    const int t = threadIdx.x;
    float h0 = rdIn(x, xrow + t, f32) + bf2f(hio[hrow + t]);
    float h1 = rdIn(x, xrow + 256 + t, f32) + bf2f(hio[hrow + 256 + t]);
    float sum = h0 + h1, sq = h0 * h0 + h1 * h1;
#pragma unroll
    for (int off = 1; off < 64; off <<= 1) {
        sum += __shfl_xor(sum, off, 64);
        sq += __shfl_xor(sq, off, 64);
    }
    __shared__ float red[8];
    int wave = t >> 6, lane = t & 63;
    if (lane == 0) { red[wave] = sum; red[wave + 4] = sq; }
    __syncthreads();
    sum = red[0] + red[1] + red[2] + red[3];
    sq = red[4] + red[5] + red[6] + red[7];
    float mu = sum * (1.f / 512.f);
    float var = sq * (1.f / 512.f) - mu * mu;
    float rs = rsqrtf(var + 1e-5f);
    float v0 = (h0 - mu) * rs * rdIn(g, t, f32) + rdIn(bta, t, f32);
    float v1 = (h1 - mu) * rs * rdIn(g, 256 + t, f32) + rdIn(bta, 256 + t, f32);
    hio[hrow + t] = f2bf(v0);
    hio[hrow + 256 + t] = f2bf(v1);
}

// ---------------- launch -----------------------------------------------------
// ws layout (peak 47,710,212 B):
//   Qb[0) Kb[8.39M) Vb[16.78M)
//   Xp[33.55M..41.94M)  bf16 x, dead after QKV GEMM
//   Gs[8.39M..41.94M)   MLP strip (PANEL-MAJOR [64][8192][32]), after Xp dead
//   Wqt[41.94M) W1t[43.52M) W2t[45.61M, PANEL-MAJOR [64][512][32]) flag[47.71M)
extern "C" void kernel_launch(void* const* d_in, const int* in_sizes, int n_in,
                              void* d_out, int out_size, void* d_ws, size_t ws_size,
                              hipStream_t stream) {
    const void* x   = d_in[0];
    const void* Wq  = d_in[2];
    const void* bq  = d_in[3];
    const void* Wk  = d_in[4];
    const void* bk  = d_in[5];
    const void* Wv  = d_in[6];
    const void* bv  = d_in[7];
    const void* lng = d_in[14];
    const void* lnb = d_in[15];
    const void* W1  = d_in[16];
    const void* b1  = d_in[17];
    const void* W2  = d_in[18];
    const void* b2  = d_in[19];

    char* ws = (char*)d_ws;
    ushort_t* Qb  = (ushort_t*)(ws + 0);
    ushort_t* Kb  = (ushort_t*)(ws + 8388608);
    ushort_t* Vb  = (ushort_t*)(ws + 16777216);
    ushort_t* Xp  = (ushort_t*)(ws + 33554432);
    ushort_t* Gs  = (ushort_t*)(ws + 8388608);
    ushort_t* Wqt = (ushort_t*)(ws + 41943040);
    ushort_t* W1t = (ushort_t*)(ws + 43515904);
    ushort_t* W2t = (ushort_t*)(ws + 45613056);
    int*      flg = (int*)(ws + 47710208);

    pre_kernel<<<dim3(4864), dim3(256), 0, stream>>>(
        x, Wq, Wk, Wv, W1, W2, Xp, Wqt, W1t, W2t, flg);

    const float scale = 0.125f;  // 1/sqrt(64)
    gemm128_kernel<3><<<dim3(768), dim3(256), 0, stream>>>(
        Xp, Wqt, bq, bk, bv, Qb, 512, scale, flg);

    attn_mfma_kernel<<<dim3(1024), dim3(256), 0, stream>>>(Qb, Kb, Vb);

    ln_kernel<<<dim3(8190), dim3(256), 0, stream>>>(x, Qb, lng, lnb, flg);

    gemm128_kernel<1><<<dim3(1024), dim3(256), 0, stream>>>(
        Qb, W1t, b1, b1, b1, Gs, 512, 1.0f, flg);
    gemm_splitk_kernel<<<dim3(256), dim3(512), 0, stream>>>(
        Gs, W2t, b2, d_out, Qb, flg);
}

// Round 11
// 252.169 us; speedup vs baseline: 1.0154x; 1.0154x over previous
//
#include <hip/hip_runtime.h>
#include <math.h>

typedef unsigned short ushort_t;
typedef __attribute__((ext_vector_type(4))) float floatx4;
typedef __attribute__((ext_vector_type(8))) short shortx8;
typedef __attribute__((ext_vector_type(8))) unsigned short ushortx8;

__device__ __forceinline__ float bf2f(ushort_t h) {
    union { unsigned u; float f; } x; x.u = ((unsigned)h) << 16; return x.f;
}
__device__ __forceinline__ ushort_t f2bf(float f) {
    union { float f; unsigned u; } x; x.f = f;
    unsigned r = x.u + 0x7fffu + ((x.u >> 16) & 1u);
    return (ushort_t)(r >> 16);
}
__device__ __forceinline__ float rdIn(const void* p, size_t i, int f32) {
    return f32 ? ((const float*)p)[i] : bf2f(((const ushort_t*)p)[i]);
}
// async global->LDS DMA, 16 B per lane (dest must be wave-uniform base + lane*16)
__device__ __forceinline__ void gload16(const ushort_t* g, ushort_t* l) {
    __builtin_amdgcn_global_load_lds(
        (const __attribute__((address_space(1))) unsigned int*)g,
        (__attribute__((address_space(3))) unsigned int*)l, 16, 0, 0);
}
// branch-free GELU: erf via Abramowitz-Stegun 7.1.26 (|erf err| <= 1.5e-7)
__device__ __forceinline__ float gelu_f(float v) {
    float z = fabsf(v) * 0.70710678118654752f;
    float t = __builtin_amdgcn_rcpf(1.0f + 0.3275911f * z);
    float p = 1.061405429f;
    p = p * t - 1.453152027f;
    p = p * t + 1.421413741f;
    p = p * t - 0.284496736f;
    p = p * t + 0.254829592f;
    p = p * t;
    float er = 1.0f - p * __expf(-z * z);
    er = copysignf(er, v);
    return 0.5f * v * (1.0f + er);
}

// ---------------- unified pre-stage: detect + 3 transposes + prep -----------
// grid 4864 x 256thr:
//   [0,768)     transpose Wq/Wk/Wv [512,512] -> Wqt[z][512][512]
//   [768,1792)  transpose W1 [512,2048]      -> W1t[2048][512]
//   [1792,2816) transpose W2 [2048,512]      -> W2P panel-major [64][512][32]
//   [2816,4864) prep x [2,4095,512] raw      -> Xp [2,4096,512] bf16
// dtype detect inlined per-block; block 0 publishes flg for downstream.
__global__ __launch_bounds__(256) void pre_kernel(
    const void* __restrict__ x, const void* __restrict__ Wq,
    const void* __restrict__ Wk, const void* __restrict__ Wv,
    const void* __restrict__ W1, const void* __restrict__ W2,
    ushort_t* __restrict__ Xp, ushort_t* __restrict__ Wqt,
    ushort_t* __restrict__ W1t, ushort_t* __restrict__ W2t,
    int* __restrict__ flg) {
    const int t = threadIdx.x;
    const int b = blockIdx.x;

    __shared__ int cnt;
    __shared__ ushort_t tile[32][33];
    if (t == 0) cnt = 0;
    __syncthreads();
    {
        ushort_t v = ((const ushort_t*)x)[t];
        int e = (v >> 7) & 0xff;
        int ok = (e >= 100 && e <= 150) || (v == 0);
        atomicAdd(&cnt, ok);
    }
    __syncthreads();
    const int f32 = (cnt >= 240) ? 0 : 1;
    if (b == 0 && t == 0) flg[0] = f32;

    if (b < 2816) {
        const void* in;
        ushort_t* out;
        int R, C, panel, bx, by, z = 0;
        if (b < 768) {
            z = b >> 8;
            int inner = b & 255;
            in = (z == 0) ? Wq : (z == 1) ? Wk : Wv;
            out = Wqt; R = 512; C = 512; panel = 0;
            bx = inner & 15; by = inner >> 4;
        } else if (b < 1792) {
            int inner = b - 768;
            in = W1; out = W1t; R = 512; C = 2048; panel = 0;
            bx = inner & 63; by = inner >> 6;
        } else {
            int inner = b - 1792;
            in = W2; out = W2t; R = 2048; C = 512; panel = 1;
            bx = inner & 15; by = inner >> 4;
        }
        int c0 = bx * 32, r0 = by * 32;
        int tx = t & 31, ty = t >> 5;
#pragma unroll
        for (int i = 0; i < 4; i++) {
            size_t idx = (size_t)(r0 + ty + 8 * i) * C + c0 + tx;
            tile[ty + 8 * i][tx] = f32 ? f2bf(((const float*)in)[idx])
                                       : ((const ushort_t*)in)[idx];
        }
        __syncthreads();
#pragma unroll
        for (int i = 0; i < 4; i++) {
            if (panel)
                out[((size_t)(r0 >> 5) * C + (c0 + ty + 8 * i)) * 32 + tx] =
                    tile[tx][ty + 8 * i];
            else
                out[(size_t)z * R * C + (size_t)(c0 + ty + 8 * i) * R + r0 + tx] =
                    tile[tx][ty + 8 * i];
        }
    } else {
        int i = (b - 2816) * 256 + t;
        int e = i * 8;
        int s = (e >> 9) & 4095;
        int bb = e >> 21;
        ushortx8 val = {0, 0, 0, 0, 0, 0, 0, 0};
        if (s < 4095) {
            size_t src = ((size_t)(bb * 4095 + s) << 9) + (e & 511);
            if (f32) {
                const float* p = (const float*)x + src;
                floatx4 a = *(const floatx4*)p;
                floatx4 c = *(const floatx4*)(p + 4);
                val[0] = f2bf(a[0]); val[1] = f2bf(a[1]); val[2] = f2bf(a[2]); val[3] = f2bf(a[3]);
                val[4] = f2bf(c[0]); val[5] = f2bf(c[1]); val[6] = f2bf(c[2]); val[7] = f2bf(c[3]);
            } else {
                val = *(const ushortx8*)((const ushort_t*)x + src);
            }
        }
        *(ushortx8*)&Xp[e] = val;
    }
}

// ---------------- 128x128 GEMM for K=512 (QKV) ------------------------------
// splitk schedule minus the split: 256 thr = 4 waves (2x2 of 64x64,
// acc[4][4]), BK=32 -> KT=16, 4-deep LDS ring (64 KiB -> 2 blocks/CU),
// counted vmcnt(8), one s_barrier/step, setprio, chunk-XOR swizzle.
// Used for QKV only (grid 768 = full CU coverage; gemm8p's 192 was 75%).
// EPI 3: QKV merged out + bias (+scale on Q); 128 | 512 so idx=n0>>9 uniform.
template<int EPI>
__global__ __launch_bounds__(256, 2) void gemm128_kernel(
    const ushort_t* __restrict__ A, const ushort_t* __restrict__ Bt,
    const void* __restrict__ bias0, const void* __restrict__ bias1,
    const void* __restrict__ bias2, void* outp,
    int K, float scale, const int* __restrict__ flag) {
    const int f32 = flag[0];
    __shared__ __align__(16) ushort_t SH[32768];   // 64 KiB
    const int t = threadIdx.x;
    const int lane = t & 63, wave = t >> 6;
    const int wr = (wave >> 1) & 1, wc = wave & 1;
    const int l16 = lane & 15, quad = lane >> 4;
    const int pc16 = (quad ^ ((l16 >> 1) & 3)) * 8;

    const int nwg = gridDim.x;
    const int bid = blockIdx.x;
    const int cpx = nwg >> 3;
    const int sb = (bid & 7) * cpx + (bid >> 3);
    const int m0 = (sb & 63) * 128, n0 = (sb >> 6) * 128;

    const int sr = t >> 2;                           // 0..63
    const int sc8 = ((t & 3) ^ ((t >> 3) & 3)) * 8;  // pre-swizzled src chunk
    const ushort_t* Ag = A + (size_t)(m0 + sr) * K + sc8;
    const ushort_t* Bg = Bt + (size_t)(n0 + sr) * K + sc8;
    ushort_t* Sd = SH + t * 8;

    auto STAGE = [&](int kt) {
        const int b = kt & 3;
        gload16(Ag + kt * 32,                  Sd + b * 4096);
        gload16(Ag + (size_t)64 * K + kt * 32, Sd + b * 4096 + 2048);
        gload16(Bg + kt * 32,                  Sd + 16384 + b * 4096);
        gload16(Bg + (size_t)64 * K + kt * 32, Sd + 16384 + b * 4096 + 2048);
    };

    floatx4 acc[4][4];
#pragma unroll
    for (int i = 0; i < 4; i++)
#pragma unroll
        for (int j = 0; j < 4; j++)
#pragma unroll
            for (int r = 0; r < 4; r++) acc[i][j][r] = 0.f;

    const int KT = K / 32;   // 16
    STAGE(0); STAGE(1); STAGE(2);

    for (int kt = 0; kt < KT; kt++) {
        if (kt + 2 < KT)      asm volatile("s_waitcnt vmcnt(8)" ::: "memory");
        else if (kt + 1 < KT) asm volatile("s_waitcnt vmcnt(4)" ::: "memory");
        else                  asm volatile("s_waitcnt vmcnt(0)" ::: "memory");
        __builtin_amdgcn_s_barrier();
        asm volatile("" ::: "memory");
        if (kt + 3 < KT) STAGE(kt + 3);   // overwrites buf[(kt-1)&3]: reads done

        const int ab = (kt & 3) * 4096;
        shortx8 af[4], bfr[4];
#pragma unroll
        for (int nf = 0; nf < 4; nf++)
            bfr[nf] = *(const shortx8*)&SH[16384 + ab + (wc * 64 + nf * 16 + l16) * 32 + pc16];
#pragma unroll
        for (int mf = 0; mf < 4; mf++)
            af[mf] = *(const shortx8*)&SH[ab + (wr * 64 + mf * 16 + l16) * 32 + pc16];

        __builtin_amdgcn_s_setprio(1);
#pragma unroll
        for (int mf = 0; mf < 4; mf++)
#pragma unroll
            for (int nf = 0; nf < 4; nf++)
                acc[mf][nf] = __builtin_amdgcn_mfma_f32_16x16x32_bf16(
                    af[mf], bfr[nf], acc[mf][nf], 0, 0, 0);
        __builtin_amdgcn_s_setprio(0);
    }

    float bias[4];
    float scl = 1.0f;
    {
        int idx = n0 >> 9;
        const void* bp = (idx == 0) ? bias0 : (idx == 1) ? bias1 : bias2;
#pragma unroll
        for (int j = 0; j < 4; j++)
            bias[j] = rdIn(bp, (n0 & 511) + wc * 64 + j * 16 + l16, f32);
        scl = (idx == 0) ? scale : 1.0f;
    }

#pragma unroll
    for (int i = 0; i < 4; i++) {
#pragma unroll
        for (int j = 0; j < 4; j++) {
#pragma unroll
            for (int r = 0; r < 4; r++) {
                int m = m0 + wr * 64 + i * 16 + quad * 4 + r;
                int n = n0 + wc * 64 + j * 16 + l16;
                float v = acc[i][j][r] + bias[j];
                ((ushort_t*)outp)[(size_t)(n0 >> 9) * 4194304 +
                                  (size_t)m * 512 + (n & 511)] = f2bf(v * scl);
            }
        }
    }
}

// ---------------- 8-phase 256x256 GEMM (MLP1; K=512) ------------------------
// m201-style schedule. BK=64 as 2 ks-halves, 512 thr = 8 waves (2Mx4N),
// wave tile 128x64, acc[8][4]. LDS 128 KiB. Counted vmcnt(4), 2 barriers/kt.
// EPI 1: gelu(v+bias), written PANEL-MAJOR Gs2[N/32][M][32] (MLP2 contract).
template<int EPI>
__global__ __launch_bounds__(512, 2) void gemm8p_kernel(
    const ushort_t* __restrict__ A, const ushort_t* __restrict__ Bt,
    const void* __restrict__ bias0, const void* __restrict__ bias1,
    const void* __restrict__ bias2, void* outp,
    int M, int N, int K, float scale, const int* __restrict__ flag) {
    const int f32 = flag[0];
    __shared__ __align__(16) ushort_t SH[65536];   // 128 KiB
    const int t = threadIdx.x;
    const int lane = t & 63, wave = t >> 6;
    const int wr = wave >> 2, wc = wave & 3;       // 2 x 4 wave grid
    const int l16 = lane & 15, quad = lane >> 4;
    const int pc16 = (quad ^ ((l16 >> 1) & 3)) * 8;  // swizzled 16B chunk (ushorts)

    // XCD-aware block swizzle (grids are multiples of 8)
    const int gx = gridDim.x;
    int nwg = gx * gridDim.y;
    int bid = blockIdx.x + gx * blockIdx.y;
    int cpx = nwg >> 3;
    int sb = (bid & 7) * cpx + (bid >> 3);
    const int m0 = (sb % gx) * 256;
    const int n0 = (sb / gx) * 256;

    const int sr = t >> 2;
    const int lc = ((t & 3) ^ ((t >> 3) & 3)) * 8;   // pre-swizzled source chunk
    const ushort_t* Ag = A + (size_t)(m0 + sr) * K + lc;
    const ushort_t* Bg = Bt + (size_t)(n0 + sr) * K + lc;
    ushort_t* Sd = SH + t * 8;

    auto STAGE_A = [&](int buf, int kt, int ks) {
        const ushort_t* g = Ag + kt * 64 + ks * 32;
        int d = buf * 16384 + ks * 8192;
        gload16(g,                   Sd + d);
        gload16(g + (size_t)128 * K, Sd + d + 4096);
    };
    auto STAGE_B = [&](int buf, int kt, int ks) {
        const ushort_t* g = Bg + kt * 64 + ks * 32;
        int d = 32768 + buf * 16384 + ks * 8192;
        gload16(g,                   Sd + d);
        gload16(g + (size_t)128 * K, Sd + d + 4096);
    };

    floatx4 acc[8][4];
#pragma unroll
    for (int i = 0; i < 8; i++)
#pragma unroll
        for (int j = 0; j < 4; j++)
#pragma unroll
            for (int r = 0; r < 4; r++) acc[i][j][r] = 0.f;

    shortx8 af[4], bfr[4];
    auto LDB = [&](int buf, int ks) {
#pragma unroll
        for (int nf = 0; nf < 4; nf++)
            bfr[nf] = *(const shortx8*)&SH[32768 + buf * 16384 + ks * 8192 +
                                           (wc * 64 + nf * 16 + l16) * 32 + pc16];
    };
    auto LDA = [&](int buf, int ks, int h) {
#pragma unroll
        for (int i = 0; i < 4; i++)
            af[i] = *(const shortx8*)&SH[buf * 16384 + ks * 8192 +
                                         (wr * 128 + (h * 4 + i) * 16 + l16) * 32 + pc16];
    };
    auto FMA = [&](int h) {
        __builtin_amdgcn_s_setprio(1);
#pragma unroll
        for (int i = 0; i < 4; i++)
#pragma unroll
            for (int nf = 0; nf < 4; nf++)
                acc[h * 4 + i][nf] = __builtin_amdgcn_mfma_f32_16x16x32_bf16(
                    af[i], bfr[nf], acc[h * 4 + i][nf], 0, 0, 0);
        __builtin_amdgcn_s_setprio(0);
    };

    const int KT = K / 64;
    STAGE_A(0, 0, 0); STAGE_B(0, 0, 0);
    STAGE_A(0, 0, 1); STAGE_B(0, 0, 1);

    for (int kt = 0; kt < KT; kt++) {
        const int b = kt & 1, nb = b ^ 1;
        const bool pf = (kt + 1 < KT);
        asm volatile("s_waitcnt vmcnt(4)" ::: "memory");
        __builtin_amdgcn_s_barrier();
        asm volatile("" ::: "memory");
        if (pf) STAGE_A(nb, kt + 1, 0);
        LDB(b, 0); LDA(b, 0, 0);
        FMA(0);
        if (pf) STAGE_B(nb, kt + 1, 0);
        LDA(b, 0, 1);
        FMA(1);
        if (pf) asm volatile("s_waitcnt vmcnt(4)" ::: "memory");
        else    asm volatile("s_waitcnt vmcnt(0)" ::: "memory");
        __builtin_amdgcn_s_barrier();
        asm volatile("" ::: "memory");
        if (pf) STAGE_A(nb, kt + 1, 1);
        LDB(b, 1); LDA(b, 1, 0);
        FMA(0);
        if (pf) STAGE_B(nb, kt + 1, 1);
        LDA(b, 1, 1);
        FMA(1);
    }

    // ---------------- epilogue: process acc, bounce via LDS, coalesced store
    __syncthreads();   // all LDS reads done before overwrite

    float bias[4];
    float scl = 1.0f;
    if (EPI == 3) {
        int idx = n0 >> 9;
        const void* bp = (idx == 0) ? bias0 : (idx == 1) ? bias1 : bias2;
#pragma unroll
        for (int nf = 0; nf < 4; nf++)
            bias[nf] = rdIn(bp, (n0 & 511) + wc * 64 + nf * 16 + l16, f32);
        scl = (idx == 0) ? scale : 1.0f;
    } else {
#pragma unroll
        for (int nf = 0; nf < 4; nf++)
            bias[nf] = rdIn(bias0, n0 + wc * 64 + nf * 16 + l16, f32);
    }

#pragma unroll
    for (int mf = 0; mf < 8; mf++) {
#pragma unroll
        for (int nf = 0; nf < 4; nf++) {
#pragma unroll
            for (int r = 0; r < 4; r++) {
                int row = wr * 128 + mf * 16 + quad * 4 + r;
                float v = acc[mf][nf][r] + bias[nf];
                if (EPI == 3) v *= scl;
                else          v = gelu_f(v);
                int ch = wc * 8 + nf * 2 + (l16 >> 3);
                SH[row * 256 + ((ch ^ (row & 7)) * 8) + (l16 & 7)] = f2bf(v);
            }
        }
    }
    __syncthreads();

    if (EPI == 3) {
        ushort_t* ob = (ushort_t*)outp + (size_t)(n0 >> 9) * 4194304 + (n0 & 511);
#pragma unroll
        for (int i = 0; i < 16; i++) {
            int j = i * 512 + t;
            int row = j >> 5, ch = j & 31;
            ushortx8 vv = *(const ushortx8*)&SH[row * 256 + ((ch ^ (row & 7)) * 8)];
            *(ushortx8*)&ob[(size_t)(m0 + row) * 512 + ch * 8] = vv;
        }
    } else {
        // panel-major: Gs2[(n>>5)][m][n&31]
        ushort_t* ob = (ushort_t*)outp;
        const size_t pb0 = (size_t)(n0 >> 5) * 262144 + (size_t)m0 * 32;
#pragma unroll
        for (int i = 0; i < 16; i++) {
            int j = i * 512 + t;
            int p = j >> 10, row = (j >> 2) & 255, c = j & 3;
            int ch = p * 4 + c;
            ushortx8 vv = *(const ushortx8*)&SH[row * 256 + ((ch ^ (row & 7)) * 8)];
            *(ushortx8*)&ob[pb0 + (size_t)p * 262144 + (size_t)row * 32 + c * 8] = vv;
        }
    }
}

// ---------------- split-K 128x128 GEMM for MLP2, dense panel staging --------
// grid 256 = 64 mt x 4 nt, 8 waves (kh, wr, wc) w/ 64x64 subtiles, BK=32,
// KT=32, 4-deep LDS ring, counted vmcnt(8), one barrier/step, in-LDS split-K
// reduce. A = Gs2[K/32][8192][32] and B = W2P[K/32][512][32] are PANEL-MAJOR:
// each of the 4 DMAs per step reads an 8 KB fully-contiguous block.
__global__ __launch_bounds__(512, 2) void gemm_splitk_kernel(
    const ushort_t* __restrict__ A, const ushort_t* __restrict__ Bt,
    const void* __restrict__ bias0, void* outp,
    const ushort_t* __restrict__ resid, const int* __restrict__ flag) {
    const int f32 = flag[0];
    __shared__ __align__(16) ushort_t SH[65536];   // 128 KiB
    const int t = threadIdx.x;
    const int lane = t & 63, wave = t >> 6;
    const int kh = wave >> 2, wr = (wave >> 1) & 1, wc = wave & 1;
    const int l16 = lane & 15, quad = lane >> 4;
    const int pc16 = (quad ^ ((l16 >> 1) & 3)) * 8;

    const int bid = blockIdx.x;
    const int xcd = bid & 7, i5 = bid >> 3;
    const int nt = xcd >> 1;
    const int mt = (xcd & 1) * 32 + i5;
    const int m0 = mt * 128, n0 = nt * 128;

    const int sr = t >> 2;                           // 0..127
    const int sc8 = ((t & 3) ^ ((t >> 3) & 3)) * 8;  // pre-swizzled chunk
    const ushort_t* Ag = A + (size_t)(m0 + sr) * 32 + sc8;
    const ushort_t* Bg = Bt + (size_t)(n0 + sr) * 32 + sc8;
    ushort_t* Sd = SH + t * 8;

    auto STAGE = [&](int kt) {
        const int b = kt & 3;
        gload16(Ag + (size_t)kt * 262144,        Sd + b * 8192);
        gload16(Ag + (size_t)(32 + kt) * 262144, Sd + b * 8192 + 4096);
        gload16(Bg + (size_t)kt * 16384,         Sd + 32768 + b * 8192);
        gload16(Bg + (size_t)(32 + kt) * 16384,  Sd + 32768 + b * 8192 + 4096);
    };

    floatx4 acc[4][4];
#pragma unroll
    for (int i = 0; i < 4; i++)
#pragma unroll
        for (int j = 0; j < 4; j++)
#pragma unroll
            for (int r = 0; r < 4; r++) acc[i][j][r] = 0.f;

    const int KT = 32;
    STAGE(0); STAGE(1); STAGE(2);

    for (int kt = 0; kt < KT; kt++) {
        if (kt + 2 < KT)      asm volatile("s_waitcnt vmcnt(8)" ::: "memory");
        else if (kt + 1 < KT) asm volatile("s_waitcnt vmcnt(4)" ::: "memory");
        else                  asm volatile("s_waitcnt vmcnt(0)" ::: "memory");
        __builtin_amdgcn_s_barrier();
        asm volatile("" ::: "memory");
        if (kt + 3 < KT) STAGE(kt + 3);   // overwrites buf[(kt-1)&3]: reads done

        const int ab = (kt & 3) * 8192 + kh * 4096;
        shortx8 af[4], bfr[4];
#pragma unroll
        for (int nf = 0; nf < 4; nf++)
            bfr[nf] = *(const shortx8*)&SH[32768 + ab + (wc * 64 + nf * 16 + l16) * 32 + pc16];
#pragma unroll
        for (int mf = 0; mf < 4; mf++)
            af[mf] = *(const shortx8*)&SH[ab + (wr * 64 + mf * 16 + l16) * 32 + pc16];

        __builtin_amdgcn_s_setprio(1);
#pragma unroll
        for (int mf = 0; mf < 4; mf++)
#pragma unroll
            for (int nf = 0; nf < 4; nf++)
                acc[mf][nf] = __builtin_amdgcn_mfma_f32_16x16x32_bf16(
                    af[mf], bfr[nf], acc[mf][nf], 0, 0, 0);
        __builtin_amdgcn_s_setprio(0);
    }

    // ---------------- in-LDS split-K reduce + epi-2 store -------------------
    __syncthreads();                       // all ds reads done before overwrite
    float* RED = (float*)SH;               // 64 KiB fp32 scratch
    if (kh == 1) {
        const int base = ((wave & 3) * 64 + lane) * 16;
#pragma unroll
        for (int i = 0; i < 4; i++)
#pragma unroll
            for (int j = 0; j < 4; j++) {
                int k2 = (i * 4 + j + l16) & 15;   // per-lane rotate: spread banks
                *(floatx4*)&RED[(base + k2) * 4] = acc[i][j];
            }
    }
    __syncthreads();
    if (kh == 0) {
        const int base = (wave * 64 + lane) * 16;
#pragma unroll
        for (int i = 0; i < 4; i++)
#pragma unroll
            for (int j = 0; j < 4; j++) {
                int k2 = (i * 4 + j + l16) & 15;
                floatx4 p = *(const floatx4*)&RED[(base + k2) * 4];
#pragma unroll
                for (int r = 0; r < 4; r++) acc[i][j][r] += p[r];
            }
#pragma unroll
        for (int i = 0; i < 4; i++) {
#pragma unroll
            for (int j = 0; j < 4; j++) {
#pragma unroll
                for (int r = 0; r < 4; r++) {
                    int m = m0 + wr * 64 + i * 16 + quad * 4 + r;
                    int n = n0 + wc * 64 + j * 16 + l16;
                    int bb = m >> 12, s = m & 4095;
                    if (s < 4095) {
                        float v = acc[i][j][r] + rdIn(bias0, n, f32) +
                                  bf2f(resid[(size_t)m * 512 + n]);
                        size_t oidx = ((size_t)bb * 4095 + s) * 512 + n;
                        if (f32) ((float*)outp)[oidx] = v;
                        else     ((ushort_t*)outp)[oidx] = f2bf(v);
                    }
                }
            }
        }
    }
}

// ---------------- MFMA windowed attention + global key ----------------------
#define ALD 344

__global__ __launch_bounds__(256) void attn_mfma_kernel(
    ushort_t* Q, const ushort_t* __restrict__ Kx, const ushort_t* __restrict__ Vx) {
    __shared__ ushort_t Pl[64][ALD];
    __shared__ ushort_t Vt[2][64][40];
    __shared__ float pgl[64];

    const int t = threadIdx.x;
    const int lane = t & 63, w = t >> 6;
    const int l16 = lane & 15, quad = lane >> 4;
    const int bid = blockIdx.x;
    const int qt = bid & 63;
    const int h = (bid >> 6) & 7;
    const int b = bid >> 9;
    const int q0 = qt * 64;
    const int jmin = q0 - 128;
    const size_t base = ((size_t)b * 4096) * 512 + (size_t)h * 64;

    const int qw = q0 + w * 16;
    const int lo = qw - 128, hi = qw + 15 + 128;

    shortx8 qf0, qf1;
    {
        const ushort_t* qp = Q + base + (size_t)(qw + l16) * 512 + quad * 8;
        qf0 = *(const shortx8*)(qp);
        qf1 = *(const shortx8*)(qp + 32);
    }

    floatx4 s[21];
#pragma unroll
    for (int i = 0; i < 21; i++)
#pragma unroll
        for (int r = 0; r < 4; r++) s[i][r] = 0.f;

#pragma unroll
    for (int tt = 0; tt < 20; tt++) {
        int jt = jmin + tt * 16;
        if (jt + 15 < lo || jt > hi) continue;
        int key = jt + l16;
        int kcl = min(max(key, 0), 4094);
        const ushort_t* kp = Kx + base + (size_t)kcl * 512 + quad * 8;
        shortx8 k0 = *(const shortx8*)(kp);
        shortx8 k1 = *(const shortx8*)(kp + 32);
        s[tt] = __builtin_amdgcn_mfma_f32_16x16x32_bf16(qf0, k0, s[tt], 0, 0, 0);
        s[tt] = __builtin_amdgcn_mfma_f32_16x16x32_bf16(qf1, k1, s[tt], 0, 0, 0);
    }
    {
        const ushort_t* kp = Kx + base + (size_t)4095 * 512 + quad * 8;
        shortx8 k0 = *(const shortx8*)(kp);
        shortx8 k1 = *(const shortx8*)(kp + 32);
        s[20] = __builtin_amdgcn_mfma_f32_16x16x32_bf16(qf0, k0, s[20], 0, 0, 0);
        s[20] = __builtin_amdgcn_mfma_f32_16x16x32_bf16(qf1, k1, s[20], 0, 0, 0);
    }

#pragma unroll
    for (int tt = 0; tt < 20; tt++) {
        int j = jmin + tt * 16 + l16;
        bool okj = (j >= 0) && (j <= 4094);
#pragma unroll
        for (int r = 0; r < 4; r++) {
            int q = qw + quad * 4 + r;
            bool ok = okj && (j - q <= 128) && (q - j <= 128);
            if (!ok) s[tt][r] = -1e30f;
        }
    }
    if (l16 != 0) {
#pragma unroll
        for (int r = 0; r < 4; r++) s[20][r] = -1e30f;
    }

    floatx4 mx = s[0];
#pragma unroll
    for (int tt = 1; tt < 21; tt++)
#pragma unroll
        for (int r = 0; r < 4; r++) mx[r] = fmaxf(mx[r], s[tt][r]);
#pragma unroll
    for (int off = 1; off < 16; off <<= 1)
#pragma unroll
        for (int r = 0; r < 4; r++) mx[r] = fmaxf(mx[r], __shfl_xor(mx[r], off, 64));

    floatx4 sum;
#pragma unroll
    for (int r = 0; r < 4; r++) sum[r] = 0.f;
#pragma unroll
    for (int tt = 0; tt < 21; tt++)
#pragma unroll
        for (int r = 0; r < 4; r++) {
            float e = __expf(s[tt][r] - mx[r]);
            s[tt][r] = e;
            sum[r] += e;
        }
#pragma unroll
    for (int off = 1; off < 16; off <<= 1)
#pragma unroll
        for (int r = 0; r < 4; r++) sum[r] += __shfl_xor(sum[r], off, 64);

    floatx4 inv;
#pragma unroll
    for (int r = 0; r < 4; r++) inv[r] = 1.f / sum[r];

#pragma unroll
    for (int tt = 0; tt < 20; tt++)
#pragma unroll
        for (int r = 0; r < 4; r++)
            Pl[w * 16 + quad * 4 + r][tt * 16 + l16] = f2bf(s[tt][r]);
    if (l16 == 0) {
#pragma unroll
        for (int r = 0; r < 4; r++) pgl[w * 16 + quad * 4 + r] = s[20][r];
    }

    floatx4 o[4];
#pragma unroll
    for (int nt = 0; nt < 4; nt++)
#pragma unroll
        for (int r = 0; r < 4; r++) o[nt][r] = 0.f;

    const int ck = t & 31, cd = t >> 5;
    ushortx8 vreg;
    {
        int row = min(max(jmin + ck, 0), 4095);
        vreg = *(const ushortx8*)&Vx[base + (size_t)row * 512 + cd * 8];
    }
    for (int c = 0; c < 10; c++) {
#pragma unroll
        for (int e = 0; e < 8; e++) Vt[c & 1][cd * 8 + e][ck] = vreg[e];
        if (c < 9) {
            int row = min(max(jmin + (c + 1) * 32 + ck, 0), 4095);
            vreg = *(const ushortx8*)&Vx[base + (size_t)row * 512 + cd * 8];
        }
        __syncthreads();
        int jc = jmin + c * 32;
        if (jc + 31 >= lo && jc <= hi) {
            shortx8 pf = *(const shortx8*)&Pl[w * 16 + l16][c * 32 + quad * 8];
#pragma unroll
            for (int nt = 0; nt < 4; nt++) {
                shortx8 vf = *(const shortx8*)&Vt[c & 1][nt * 16 + l16][quad * 8];
                o[nt] = __builtin_amdgcn_mfma_f32_16x16x32_bf16(pf, vf, o[nt], 0, 0, 0);
            }
        }
    }

#pragma unroll
    for (int nt = 0; nt < 4; nt++) {
        float vg = bf2f(Vx[base + (size_t)4095 * 512 + nt * 16 + l16]);
#pragma unroll
        for (int r = 0; r < 4; r++) {
            float pg = pgl[w * 16 + quad * 4 + r];
            float val = (o[nt][r] + pg * vg) * inv[r];
            Q[base + (size_t)(qw + quad * 4 + r) * 512 + nt * 16 + l16] = f2bf(val);
        }
    }
}

// ---------------- residual + LayerNorm, in-place on hio ---------------------
// Reads the residual from Xp (bf16, same values QKV consumed) instead of raw
// fp32 x: 17 MB less traffic, identical indexing as hio. Xp is still live
// here (MLP1 overwrites the Gs/Xp region only after ln completes).
__global__ __launch_bounds__(256) void ln_kernel(
    const ushort_t* __restrict__ xp, ushort_t* hio,
    const void* __restrict__ g, const void* __restrict__ bta,
    const int* __restrict__ flag) {
    const int f32 = flag[0];
    const int r = blockIdx.x;
    const int b = (r >= 4095) ? 1 : 0;
    const int s = r - b * 4095;
    const size_t hrow = ((size_t)b * 4096 + s) * 512;
    const int t = threadIdx.x;
    float h0 = bf2f(xp[hrow + t]) + bf2f(hio[hrow + t]);
    float h1 = bf2f(xp[hrow + 256 + t]) + bf2f(hio[hrow + 256 + t]);
    float sum = h0 + h1, sq = h0 * h0 + h1 * h1;
#pragma unroll
    for (int off = 1; off < 64; off <<= 1) {
        sum += __shfl_xor(sum, off, 64);
        sq += __shfl_xor(sq, off, 64);
    }
    __shared__ float red[8];
    int wave = t >> 6, lane = t & 63;
    if (lane == 0) { red[wave] = sum; red[wave + 4] = sq; }
    __syncthreads();
    sum = red[0] + red[1] + red[2] + red[3];
    sq = red[4] + red[5] + red[6] + red[7];
    float mu = sum * (1.f / 512.f);
    float var = sq * (1.f / 512.f) - mu * mu;
    float rs = rsqrtf(var + 1e-5f);
    float v0 = (h0 - mu) * rs * rdIn(g, t, f32) + rdIn(bta, t, f32);
    float v1 = (h1 - mu) * rs * rdIn(g, 256 + t, f32) + rdIn(bta, 256 + t, f32);
    hio[hrow + t] = f2bf(v0);
    hio[hrow + 256 + t] = f2bf(v1);
}

// ---------------- launch -----------------------------------------------------
// ws layout (peak 47,710,212 B):
//   Qb[0) Kb[8.39M) Vb[16.78M)
//   Xp[33.55M..41.94M)  bf16 x; read by QKV and ln, dead after ln
//   Gs[8.39M..41.94M)   MLP strip (PANEL-MAJOR [64][8192][32]), after Xp dead
//   Wqt[41.94M) W1t[43.52M) W2t[45.61M, PANEL-MAJOR [64][512][32]) flag[47.71M)
extern "C" void kernel_launch(void* const* d_in, const int* in_sizes, int n_in,
                              void* d_out, int out_size, void* d_ws, size_t ws_size,
                              hipStream_t stream) {
    const void* x   = d_in[0];
    const void* Wq  = d_in[2];
    const void* bq  = d_in[3];
    const void* Wk  = d_in[4];
    const void* bk  = d_in[5];
    const void* Wv  = d_in[6];
    const void* bv  = d_in[7];
    const void* lng = d_in[14];
    const void* lnb = d_in[15];
    const void* W1  = d_in[16];
    const void* b1  = d_in[17];
    const void* W2  = d_in[18];
    const void* b2  = d_in[19];

    char* ws = (char*)d_ws;
    ushort_t* Qb  = (ushort_t*)(ws + 0);
    ushort_t* Kb  = (ushort_t*)(ws + 8388608);
    ushort_t* Vb  = (ushort_t*)(ws + 16777216);
    ushort_t* Xp  = (ushort_t*)(ws + 33554432);
    ushort_t* Gs  = (ushort_t*)(ws + 8388608);
    ushort_t* Wqt = (ushort_t*)(ws + 41943040);
    ushort_t* W1t = (ushort_t*)(ws + 43515904);
    ushort_t* W2t = (ushort_t*)(ws + 45613056);
    int*      flg = (int*)(ws + 47710208);

    pre_kernel<<<dim3(4864), dim3(256), 0, stream>>>(
        x, Wq, Wk, Wv, W1, W2, Xp, Wqt, W1t, W2t, flg);

    const float scale = 0.125f;  // 1/sqrt(64)
    gemm128_kernel<3><<<dim3(768), dim3(256), 0, stream>>>(
        Xp, Wqt, bq, bk, bv, Qb, 512, scale, flg);

    attn_mfma_kernel<<<dim3(1024), dim3(256), 0, stream>>>(Qb, Kb, Vb);

    ln_kernel<<<dim3(8190), dim3(256), 0, stream>>>(Xp, Qb, lng, lnb, flg);

    gemm8p_kernel<1><<<dim3(32, 8), dim3(512), 0, stream>>>(
        Qb, W1t, b1, b1, b1, Gs, 8192, 2048, 512, 1.0f, flg);
    gemm_splitk_kernel<<<dim3(256), dim3(512), 0, stream>>>(
        Gs, W2t, b2, d_out, Qb, flg);
}

// Round 12
// 251.880 us; speedup vs baseline: 1.0166x; 1.0011x over previous
//
#include <hip/hip_runtime.h>
#include <math.h>

typedef unsigned short ushort_t;
typedef __attribute__((ext_vector_type(4))) float floatx4;
typedef __attribute__((ext_vector_type(8))) short shortx8;
typedef __attribute__((ext_vector_type(8))) unsigned short ushortx8;

__device__ __forceinline__ float bf2f(ushort_t h) {
    union { unsigned u; float f; } x; x.u = ((unsigned)h) << 16; return x.f;
}
__device__ __forceinline__ ushort_t f2bf(float f) {
    union { float f; unsigned u; } x; x.f = f;
    unsigned r = x.u + 0x7fffu + ((x.u >> 16) & 1u);
    return (ushort_t)(r >> 16);
}
__device__ __forceinline__ float rdIn(const void* p, size_t i, int f32) {
    return f32 ? ((const float*)p)[i] : bf2f(((const ushort_t*)p)[i]);
}
// async global->LDS DMA, 16 B per lane (dest must be wave-uniform base + lane*16)
__device__ __forceinline__ void gload16(const ushort_t* g, ushort_t* l) {
    __builtin_amdgcn_global_load_lds(
        (const __attribute__((address_space(1))) unsigned int*)g,
        (__attribute__((address_space(3))) unsigned int*)l, 16, 0, 0);
}
// branch-free GELU: erf via Abramowitz-Stegun 7.1.26 (|erf err| <= 1.5e-7)
__device__ __forceinline__ float gelu_f(float v) {
    float z = fabsf(v) * 0.70710678118654752f;
    float t = __builtin_amdgcn_rcpf(1.0f + 0.3275911f * z);
    float p = 1.061405429f;
    p = p * t - 1.453152027f;
    p = p * t + 1.421413741f;
    p = p * t - 0.284496736f;
    p = p * t + 0.254829592f;
    p = p * t;
    float er = 1.0f - p * __expf(-z * z);
    er = copysignf(er, v);
    return 0.5f * v * (1.0f + er);
}

// ---------------- unified pre-stage: detect + 3 transposes + prep -----------
// grid 4864 x 256thr:
//   [0,768)     transpose Wq/Wk/Wv [512,512] -> Wqt[z][512][512]
//   [768,1792)  transpose W1 [512,2048]      -> W1t[2048][512]
//   [1792,2816) transpose W2 [2048,512]      -> W2P panel-major [64][512][32]
//   [2816,4864) prep x [2,4095,512] raw      -> Xp [2,4096,512] bf16
// dtype detect inlined per-block; block 0 publishes flg for downstream.
__global__ __launch_bounds__(256) void pre_kernel(
    const void* __restrict__ x, const void* __restrict__ Wq,
    const void* __restrict__ Wk, const void* __restrict__ Wv,
    const void* __restrict__ W1, const void* __restrict__ W2,
    ushort_t* __restrict__ Xp, ushort_t* __restrict__ Wqt,
    ushort_t* __restrict__ W1t, ushort_t* __restrict__ W2t,
    int* __restrict__ flg) {
    const int t = threadIdx.x;
    const int b = blockIdx.x;

    __shared__ int cnt;
    __shared__ ushort_t tile[32][33];
    if (t == 0) cnt = 0;
    __syncthreads();
    {
        ushort_t v = ((const ushort_t*)x)[t];
        int e = (v >> 7) & 0xff;
        int ok = (e >= 100 && e <= 150) || (v == 0);
        atomicAdd(&cnt, ok);
    }
    __syncthreads();
    const int f32 = (cnt >= 240) ? 0 : 1;
    if (b == 0 && t == 0) flg[0] = f32;

    if (b < 2816) {
        const void* in;
        ushort_t* out;
        int R, C, panel, bx, by, z = 0;
        if (b < 768) {
            z = b >> 8;
            int inner = b & 255;
            in = (z == 0) ? Wq : (z == 1) ? Wk : Wv;
            out = Wqt; R = 512; C = 512; panel = 0;
            bx = inner & 15; by = inner >> 4;
        } else if (b < 1792) {
            int inner = b - 768;
            in = W1; out = W1t; R = 512; C = 2048; panel = 0;
            bx = inner & 63; by = inner >> 6;
        } else {
            int inner = b - 1792;
            in = W2; out = W2t; R = 2048; C = 512; panel = 1;
            bx = inner & 15; by = inner >> 4;
        }
        int c0 = bx * 32, r0 = by * 32;
        int tx = t & 31, ty = t >> 5;
#pragma unroll
        for (int i = 0; i < 4; i++) {
            size_t idx = (size_t)(r0 + ty + 8 * i) * C + c0 + tx;
            tile[ty + 8 * i][tx] = f32 ? f2bf(((const float*)in)[idx])
                                       : ((const ushort_t*)in)[idx];
        }
        __syncthreads();
#pragma unroll
        for (int i = 0; i < 4; i++) {
            if (panel)
                out[((size_t)(r0 >> 5) * C + (c0 + ty + 8 * i)) * 32 + tx] =
                    tile[tx][ty + 8 * i];
            else
                out[(size_t)z * R * C + (size_t)(c0 + ty + 8 * i) * R + r0 + tx] =
                    tile[tx][ty + 8 * i];
        }
    } else {
        int i = (b - 2816) * 256 + t;
        int e = i * 8;
        int s = (e >> 9) & 4095;
        int bb = e >> 21;
        ushortx8 val = {0, 0, 0, 0, 0, 0, 0, 0};
        if (s < 4095) {
            size_t src = ((size_t)(bb * 4095 + s) << 9) + (e & 511);
            if (f32) {
                const float* p = (const float*)x + src;
                floatx4 a = *(const floatx4*)p;
                floatx4 c = *(const floatx4*)(p + 4);
                val[0] = f2bf(a[0]); val[1] = f2bf(a[1]); val[2] = f2bf(a[2]); val[3] = f2bf(a[3]);
                val[4] = f2bf(c[0]); val[5] = f2bf(c[1]); val[6] = f2bf(c[2]); val[7] = f2bf(c[3]);
            } else {
                val = *(const ushortx8*)((const ushort_t*)x + src);
            }
        }
        *(ushortx8*)&Xp[e] = val;
    }
}

// ---------------- 8-phase 256x256 GEMM (QKV, MLP1; K=512) -------------------
// m201-style schedule. BK=64 as 2 ks-halves, 512 thr = 8 waves (2Mx4N),
// wave tile 128x64, acc[8][4]. LDS 128 KiB. Counted vmcnt(4), 2 barriers/kt.
// EPI 3: QKV merged out [3][8192][512].
// EPI 1: gelu(v+bias), written PANEL-MAJOR Gs2[N/32][M][32] (MLP2 contract).
template<int EPI>
__global__ __launch_bounds__(512, 2) void gemm8p_kernel(
    const ushort_t* __restrict__ A, const ushort_t* __restrict__ Bt,
    const void* __restrict__ bias0, const void* __restrict__ bias1,
    const void* __restrict__ bias2, void* outp,
    int M, int N, int K, float scale, const int* __restrict__ flag) {
    const int f32 = flag[0];
    __shared__ __align__(16) ushort_t SH[65536];   // 128 KiB
    const int t = threadIdx.x;
    const int lane = t & 63, wave = t >> 6;
    const int wr = wave >> 2, wc = wave & 3;       // 2 x 4 wave grid
    const int l16 = lane & 15, quad = lane >> 4;
    const int pc16 = (quad ^ ((l16 >> 1) & 3)) * 8;  // swizzled 16B chunk (ushorts)

    // XCD-aware block swizzle (grids are multiples of 8)
    const int gx = gridDim.x;
    int nwg = gx * gridDim.y;
    int bid = blockIdx.x + gx * blockIdx.y;
    int cpx = nwg >> 3;
    int sb = (bid & 7) * cpx + (bid >> 3);
    const int m0 = (sb % gx) * 256;
    const int n0 = (sb / gx) * 256;

    const int sr = t >> 2;
    const int lc = ((t & 3) ^ ((t >> 3) & 3)) * 8;   // pre-swizzled source chunk
    const ushort_t* Ag = A + (size_t)(m0 + sr) * K + lc;
    const ushort_t* Bg = Bt + (size_t)(n0 + sr) * K + lc;
    ushort_t* Sd = SH + t * 8;

    auto STAGE_A = [&](int buf, int kt, int ks) {
        const ushort_t* g = Ag + kt * 64 + ks * 32;
        int d = buf * 16384 + ks * 8192;
        gload16(g,                   Sd + d);
        gload16(g + (size_t)128 * K, Sd + d + 4096);
    };
    auto STAGE_B = [&](int buf, int kt, int ks) {
        const ushort_t* g = Bg + kt * 64 + ks * 32;
        int d = 32768 + buf * 16384 + ks * 8192;
        gload16(g,                   Sd + d);
        gload16(g + (size_t)128 * K, Sd + d + 4096);
    };

    floatx4 acc[8][4];
#pragma unroll
    for (int i = 0; i < 8; i++)
#pragma unroll
        for (int j = 0; j < 4; j++)
#pragma unroll
            for (int r = 0; r < 4; r++) acc[i][j][r] = 0.f;

    shortx8 af[4], bfr[4];
    auto LDB = [&](int buf, int ks) {
#pragma unroll
        for (int nf = 0; nf < 4; nf++)
            bfr[nf] = *(const shortx8*)&SH[32768 + buf * 16384 + ks * 8192 +
                                           (wc * 64 + nf * 16 + l16) * 32 + pc16];
    };
    auto LDA = [&](int buf, int ks, int h) {
#pragma unroll
        for (int i = 0; i < 4; i++)
            af[i] = *(const shortx8*)&SH[buf * 16384 + ks * 8192 +
                                         (wr * 128 + (h * 4 + i) * 16 + l16) * 32 + pc16];
    };
    auto FMA = [&](int h) {
        __builtin_amdgcn_s_setprio(1);
#pragma unroll
        for (int i = 0; i < 4; i++)
#pragma unroll
            for (int nf = 0; nf < 4; nf++)
                acc[h * 4 + i][nf] = __builtin_amdgcn_mfma_f32_16x16x32_bf16(
                    af[i], bfr[nf], acc[h * 4 + i][nf], 0, 0, 0);
        __builtin_amdgcn_s_setprio(0);
    };

    const int KT = K / 64;
    STAGE_A(0, 0, 0); STAGE_B(0, 0, 0);
    STAGE_A(0, 0, 1); STAGE_B(0, 0, 1);

    for (int kt = 0; kt < KT; kt++) {
        const int b = kt & 1, nb = b ^ 1;
        const bool pf = (kt + 1 < KT);
        asm volatile("s_waitcnt vmcnt(4)" ::: "memory");
        __builtin_amdgcn_s_barrier();
        asm volatile("" ::: "memory");
        if (pf) STAGE_A(nb, kt + 1, 0);
        LDB(b, 0); LDA(b, 0, 0);
        FMA(0);
        if (pf) STAGE_B(nb, kt + 1, 0);
        LDA(b, 0, 1);
        FMA(1);
        if (pf) asm volatile("s_waitcnt vmcnt(4)" ::: "memory");
        else    asm volatile("s_waitcnt vmcnt(0)" ::: "memory");
        __builtin_amdgcn_s_barrier();
        asm volatile("" ::: "memory");
        if (pf) STAGE_A(nb, kt + 1, 1);
        LDB(b, 1); LDA(b, 1, 0);
        FMA(0);
        if (pf) STAGE_B(nb, kt + 1, 1);
        LDA(b, 1, 1);
        FMA(1);
    }

    // ---------------- epilogue: process acc, bounce via LDS, coalesced store
    __syncthreads();   // all LDS reads done before overwrite

    float bias[4];
    float scl = 1.0f;
    if (EPI == 3) {
        int idx = n0 >> 9;
        const void* bp = (idx == 0) ? bias0 : (idx == 1) ? bias1 : bias2;
#pragma unroll
        for (int nf = 0; nf < 4; nf++)
            bias[nf] = rdIn(bp, (n0 & 511) + wc * 64 + nf * 16 + l16, f32);
        scl = (idx == 0) ? scale : 1.0f;
    } else {
#pragma unroll
        for (int nf = 0; nf < 4; nf++)
            bias[nf] = rdIn(bias0, n0 + wc * 64 + nf * 16 + l16, f32);
    }

#pragma unroll
    for (int mf = 0; mf < 8; mf++) {
#pragma unroll
        for (int nf = 0; nf < 4; nf++) {
#pragma unroll
            for (int r = 0; r < 4; r++) {
                int row = wr * 128 + mf * 16 + quad * 4 + r;
                float v = acc[mf][nf][r] + bias[nf];
                if (EPI == 3) v *= scl;
                else          v = gelu_f(v);
                int ch = wc * 8 + nf * 2 + (l16 >> 3);
                SH[row * 256 + ((ch ^ (row & 7)) * 8) + (l16 & 7)] = f2bf(v);
            }
        }
    }
    __syncthreads();

    if (EPI == 3) {
        ushort_t* ob = (ushort_t*)outp + (size_t)(n0 >> 9) * 4194304 + (n0 & 511);
#pragma unroll
        for (int i = 0; i < 16; i++) {
            int j = i * 512 + t;
            int row = j >> 5, ch = j & 31;
            ushortx8 vv = *(const ushortx8*)&SH[row * 256 + ((ch ^ (row & 7)) * 8)];
            *(ushortx8*)&ob[(size_t)(m0 + row) * 512 + ch * 8] = vv;
        }
    } else {
        // panel-major: Gs2[(n>>5)][m][n&31]
        ushort_t* ob = (ushort_t*)outp;
        const size_t pb0 = (size_t)(n0 >> 5) * 262144 + (size_t)m0 * 32;
#pragma unroll
        for (int i = 0; i < 16; i++) {
            int j = i * 512 + t;
            int p = j >> 10, row = (j >> 2) & 255, c = j & 3;
            int ch = p * 4 + c;
            ushortx8 vv = *(const ushortx8*)&SH[row * 256 + ((ch ^ (row & 7)) * 8)];
            *(ushortx8*)&ob[pb0 + (size_t)p * 262144 + (size_t)row * 32 + c * 8] = vv;
        }
    }
}

// ---------------- split-K 128x128 GEMM for MLP2, dense panel staging --------
// grid 256 = 64 mt x 4 nt, 8 waves (kh, wr, wc) w/ 64x64 subtiles, BK=32,
// KT=32, 4-deep LDS ring, counted vmcnt(8), one barrier/step, in-LDS split-K
// reduce. A = Gs2[K/32][8192][32] and B = W2P[K/32][512][32] are PANEL-MAJOR:
// each of the 4 DMAs per step reads an 8 KB fully-contiguous block.
__global__ __launch_bounds__(512, 2) void gemm_splitk_kernel(
    const ushort_t* __restrict__ A, const ushort_t* __restrict__ Bt,
    const void* __restrict__ bias0, void* outp,
    const ushort_t* __restrict__ resid, const int* __restrict__ flag) {
    const int f32 = flag[0];
    __shared__ __align__(16) ushort_t SH[65536];   // 128 KiB
    const int t = threadIdx.x;
    const int lane = t & 63, wave = t >> 6;
    const int kh = wave >> 2, wr = (wave >> 1) & 1, wc = wave & 1;
    const int l16 = lane & 15, quad = lane >> 4;
    const int pc16 = (quad ^ ((l16 >> 1) & 3)) * 8;

    const int bid = blockIdx.x;
    const int xcd = bid & 7, i5 = bid >> 3;
    const int nt = xcd >> 1;
    const int mt = (xcd & 1) * 32 + i5;
    const int m0 = mt * 128, n0 = nt * 128;

    const int sr = t >> 2;                           // 0..127
    const int sc8 = ((t & 3) ^ ((t >> 3) & 3)) * 8;  // pre-swizzled chunk
    const ushort_t* Ag = A + (size_t)(m0 + sr) * 32 + sc8;
    const ushort_t* Bg = Bt + (size_t)(n0 + sr) * 32 + sc8;
    ushort_t* Sd = SH + t * 8;

    auto STAGE = [&](int kt) {
        const int b = kt & 3;
        gload16(Ag + (size_t)kt * 262144,        Sd + b * 8192);
        gload16(Ag + (size_t)(32 + kt) * 262144, Sd + b * 8192 + 4096);
        gload16(Bg + (size_t)kt * 16384,         Sd + 32768 + b * 8192);
        gload16(Bg + (size_t)(32 + kt) * 16384,  Sd + 32768 + b * 8192 + 4096);
    };

    floatx4 acc[4][4];
#pragma unroll
    for (int i = 0; i < 4; i++)
#pragma unroll
        for (int j = 0; j < 4; j++)
#pragma unroll
            for (int r = 0; r < 4; r++) acc[i][j][r] = 0.f;

    const int KT = 32;
    STAGE(0); STAGE(1); STAGE(2);

    for (int kt = 0; kt < KT; kt++) {
        if (kt + 2 < KT)      asm volatile("s_waitcnt vmcnt(8)" ::: "memory");
        else if (kt + 1 < KT) asm volatile("s_waitcnt vmcnt(4)" ::: "memory");
        else                  asm volatile("s_waitcnt vmcnt(0)" ::: "memory");
        __builtin_amdgcn_s_barrier();
        asm volatile("" ::: "memory");
        if (kt + 3 < KT) STAGE(kt + 3);   // overwrites buf[(kt-1)&3]: reads done

        const int ab = (kt & 3) * 8192 + kh * 4096;
        shortx8 af[4], bfr[4];
#pragma unroll
        for (int nf = 0; nf < 4; nf++)
            bfr[nf] = *(const shortx8*)&SH[32768 + ab + (wc * 64 + nf * 16 + l16) * 32 + pc16];
#pragma unroll
        for (int mf = 0; mf < 4; mf++)
            af[mf] = *(const shortx8*)&SH[ab + (wr * 64 + mf * 16 + l16) * 32 + pc16];

        __builtin_amdgcn_s_setprio(1);
#pragma unroll
        for (int mf = 0; mf < 4; mf++)
#pragma unroll
            for (int nf = 0; nf < 4; nf++)
                acc[mf][nf] = __builtin_amdgcn_mfma_f32_16x16x32_bf16(
                    af[mf], bfr[nf], acc[mf][nf], 0, 0, 0);
        __builtin_amdgcn_s_setprio(0);
    }

    // ---------------- in-LDS split-K reduce + epi-2 store -------------------
    __syncthreads();                       // all ds reads done before overwrite
    float* RED = (float*)SH;               // 64 KiB fp32 scratch
    if (kh == 1) {
        const int base = ((wave & 3) * 64 + lane) * 16;
#pragma unroll
        for (int i = 0; i < 4; i++)
#pragma unroll
            for (int j = 0; j < 4; j++) {
                int k2 = (i * 4 + j + l16) & 15;   // per-lane rotate: spread banks
                *(floatx4*)&RED[(base + k2) * 4] = acc[i][j];
            }
    }
    __syncthreads();
    if (kh == 0) {
        const int base = (wave * 64 + lane) * 16;
#pragma unroll
        for (int i = 0; i < 4; i++)
#pragma unroll
            for (int j = 0; j < 4; j++) {
                int k2 = (i * 4 + j + l16) & 15;
                floatx4 p = *(const floatx4*)&RED[(base + k2) * 4];
#pragma unroll
                for (int r = 0; r < 4; r++) acc[i][j][r] += p[r];
            }
#pragma unroll
        for (int i = 0; i < 4; i++) {
#pragma unroll
            for (int j = 0; j < 4; j++) {
#pragma unroll
                for (int r = 0; r < 4; r++) {
                    int m = m0 + wr * 64 + i * 16 + quad * 4 + r;
                    int n = n0 + wc * 64 + j * 16 + l16;
                    int bb = m >> 12, s = m & 4095;
                    if (s < 4095) {
                        float v = acc[i][j][r] + rdIn(bias0, n, f32) +
                                  bf2f(resid[(size_t)m * 512 + n]);
                        size_t oidx = ((size_t)bb * 4095 + s) * 512 + n;
                        if (f32) ((float*)outp)[oidx] = v;
                        else     ((ushort_t*)outp)[oidx] = f2bf(v);
                    }
                }
            }
        }
    }
}

// ---------------- MFMA windowed attention + global key ----------------------
#define ALD 344

__global__ __launch_bounds__(256) void attn_mfma_kernel(
    ushort_t* Q, const ushort_t* __restrict__ Kx, const ushort_t* __restrict__ Vx) {
    __shared__ ushort_t Pl[64][ALD];
    __shared__ ushort_t Vt[2][64][40];
    __shared__ float pgl[64];

    const int t = threadIdx.x;
    const int lane = t & 63, w = t >> 6;
    const int l16 = lane & 15, quad = lane >> 4;
    const int bid = blockIdx.x;
    const int qt = bid & 63;
    const int h = (bid >> 6) & 7;
    const int b = bid >> 9;
    const int q0 = qt * 64;
    const int jmin = q0 - 128;
    const size_t base = ((size_t)b * 4096) * 512 + (size_t)h * 64;

    const int qw = q0 + w * 16;
    const int lo = qw - 128, hi = qw + 15 + 128;

    shortx8 qf0, qf1;
    {
        const ushort_t* qp = Q + base + (size_t)(qw + l16) * 512 + quad * 8;
        qf0 = *(const shortx8*)(qp);
        qf1 = *(const shortx8*)(qp + 32);
    }

    floatx4 s[21];
#pragma unroll
    for (int i = 0; i < 21; i++)
#pragma unroll
        for (int r = 0; r < 4; r++) s[i][r] = 0.f;

#pragma unroll
    for (int tt = 0; tt < 20; tt++) {
        int jt = jmin + tt * 16;
        if (jt + 15 < lo || jt > hi) continue;
        int key = jt + l16;
        int kcl = min(max(key, 0), 4094);
        const ushort_t* kp = Kx + base + (size_t)kcl * 512 + quad * 8;
        shortx8 k0 = *(const shortx8*)(kp);
        shortx8 k1 = *(const shortx8*)(kp + 32);
        s[tt] = __builtin_amdgcn_mfma_f32_16x16x32_bf16(qf0, k0, s[tt], 0, 0, 0);
        s[tt] = __builtin_amdgcn_mfma_f32_16x16x32_bf16(qf1, k1, s[tt], 0, 0, 0);
    }
    {
        const ushort_t* kp = Kx + base + (size_t)4095 * 512 + quad * 8;
        shortx8 k0 = *(const shortx8*)(kp);
        shortx8 k1 = *(const shortx8*)(kp + 32);
        s[20] = __builtin_amdgcn_mfma_f32_16x16x32_bf16(qf0, k0, s[20], 0, 0, 0);
        s[20] = __builtin_amdgcn_mfma_f32_16x16x32_bf16(qf1, k1, s[20], 0, 0, 0);
    }

#pragma unroll
    for (int tt = 0; tt < 20; tt++) {
        int j = jmin + tt * 16 + l16;
        bool okj = (j >= 0) && (j <= 4094);
#pragma unroll
        for (int r = 0; r < 4; r++) {
            int q = qw + quad * 4 + r;
            bool ok = okj && (j - q <= 128) && (q - j <= 128);
            if (!ok) s[tt][r] = -1e30f;
        }
    }
    if (l16 != 0) {
#pragma unroll
        for (int r = 0; r < 4; r++) s[20][r] = -1e30f;
    }

    floatx4 mx = s[0];
#pragma unroll
    for (int tt = 1; tt < 21; tt++)
#pragma unroll
        for (int r = 0; r < 4; r++) mx[r] = fmaxf(mx[r], s[tt][r]);
#pragma unroll
    for (int off = 1; off < 16; off <<= 1)
#pragma unroll
        for (int r = 0; r < 4; r++) mx[r] = fmaxf(mx[r], __shfl_xor(mx[r], off, 64));

    floatx4 sum;
#pragma unroll
    for (int r = 0; r < 4; r++) sum[r] = 0.f;
#pragma unroll
    for (int tt = 0; tt < 21; tt++)
#pragma unroll
        for (int r = 0; r < 4; r++) {
            float e = __expf(s[tt][r] - mx[r]);
            s[tt][r] = e;
            sum[r] += e;
        }
#pragma unroll
    for (int off = 1; off < 16; off <<= 1)
#pragma unroll
        for (int r = 0; r < 4; r++) sum[r] += __shfl_xor(sum[r], off, 64);

    floatx4 inv;
#pragma unroll
    for (int r = 0; r < 4; r++) inv[r] = 1.f / sum[r];

#pragma unroll
    for (int tt = 0; tt < 20; tt++)
#pragma unroll
        for (int r = 0; r < 4; r++)
            Pl[w * 16 + quad * 4 + r][tt * 16 + l16] = f2bf(s[tt][r]);
    if (l16 == 0) {
#pragma unroll
        for (int r = 0; r < 4; r++) pgl[w * 16 + quad * 4 + r] = s[20][r];
    }

    floatx4 o[4];
#pragma unroll
    for (int nt = 0; nt < 4; nt++)
#pragma unroll
        for (int r = 0; r < 4; r++) o[nt][r] = 0.f;

    const int ck = t & 31, cd = t >> 5;
    ushortx8 vreg;
    {
        int row = min(max(jmin + ck, 0), 4095);
        vreg = *(const ushortx8*)&Vx[base + (size_t)row * 512 + cd * 8];
    }
    for (int c = 0; c < 10; c++) {
#pragma unroll
        for (int e = 0; e < 8; e++) Vt[c & 1][cd * 8 + e][ck] = vreg[e];
        if (c < 9) {
            int row = min(max(jmin + (c + 1) * 32 + ck, 0), 4095);
            vreg = *(const ushortx8*)&Vx[base + (size_t)row * 512 + cd * 8];
        }
        __syncthreads();
        int jc = jmin + c * 32;
        if (jc + 31 >= lo && jc <= hi) {
            shortx8 pf = *(const shortx8*)&Pl[w * 16 + l16][c * 32 + quad * 8];
#pragma unroll
            for (int nt = 0; nt < 4; nt++) {
                shortx8 vf = *(const shortx8*)&Vt[c & 1][nt * 16 + l16][quad * 8];
                o[nt] = __builtin_amdgcn_mfma_f32_16x16x32_bf16(pf, vf, o[nt], 0, 0, 0);
            }
        }
    }

#pragma unroll
    for (int nt = 0; nt < 4; nt++) {
        float vg = bf2f(Vx[base + (size_t)4095 * 512 + nt * 16 + l16]);
#pragma unroll
        for (int r = 0; r < 4; r++) {
            float pg = pgl[w * 16 + quad * 4 + r];
            float val = (o[nt][r] + pg * vg) * inv[r];
            Q[base + (size_t)(qw + quad * 4 + r) * 512 + nt * 16 + l16] = f2bf(val);
        }
    }
}

// ---------------- residual + LayerNorm, in-place on hio ---------------------
// Reads the residual from Xp (bf16, same values QKV consumed) instead of raw
// fp32 x: 17 MB less traffic, identical indexing as hio. Xp is still live
// here (MLP1 overwrites the Gs/Xp region only after ln completes).
__global__ __launch_bounds__(256) void ln_kernel(
    const ushort_t* __restrict__ xp, ushort_t* hio,
    const void* __restrict__ g, const void* __restrict__ bta,
    const int* __restrict__ flag) {
    const int f32 = flag[0];
    const int r = blockIdx.x;
    const int b = (r >= 4095) ? 1 : 0;
    const int s = r - b * 4095;
    const size_t hrow = ((size_t)b * 4096 + s) * 512;
    const int t = threadIdx.x;
    float h0 = bf2f(xp[hrow + t]) + bf2f(hio[hrow + t]);
    float h1 = bf2f(xp[hrow + 256 + t]) + bf2f(hio[hrow + 256 + t]);
    float sum = h0 + h1, sq = h0 * h0 + h1 * h1;
#pragma unroll
    for (int off = 1; off < 64; off <<= 1) {
        sum += __shfl_xor(sum, off, 64);
        sq += __shfl_xor(sq, off, 64);
    }
    __shared__ float red[8];
    int wave = t >> 6, lane = t & 63;
    if (lane == 0) { red[wave] = sum; red[wave + 4] = sq; }
    __syncthreads();
    sum = red[0] + red[1] + red[2] + red[3];
    sq = red[4] + red[5] + red[6] + red[7];
    float mu = sum * (1.f / 512.f);
    float var = sq * (1.f / 512.f) - mu * mu;
    float rs = rsqrtf(var + 1e-5f);
    float v0 = (h0 - mu) * rs * rdIn(g, t, f32) + rdIn(bta, t, f32);
    float v1 = (h1 - mu) * rs * rdIn(g, 256 + t, f32) + rdIn(bta, 256 + t, f32);
    hio[hrow + t] = f2bf(v0);
    hio[hrow + 256 + t] = f2bf(v1);
}

// ---------------- launch -----------------------------------------------------
// ws layout (peak 47,710,212 B):
//   Qb[0) Kb[8.39M) Vb[16.78M)
//   Xp[33.55M..41.94M)  bf16 x; read by QKV and ln, dead after ln
//   Gs[8.39M..41.94M)   MLP strip (PANEL-MAJOR [64][8192][32]), after Xp dead
//   Wqt[41.94M) W1t[43.52M) W2t[45.61M, PANEL-MAJOR [64][512][32]) flag[47.71M)
extern "C" void kernel_launch(void* const* d_in, const int* in_sizes, int n_in,
                              void* d_out, int out_size, void* d_ws, size_t ws_size,
                              hipStream_t stream) {
    const void* x   = d_in[0];
    const void* Wq  = d_in[2];
    const void* bq  = d_in[3];
    const void* Wk  = d_in[4];
    const void* bk  = d_in[5];
    const void* Wv  = d_in[6];
    const void* bv  = d_in[7];
    const void* lng = d_in[14];
    const void* lnb = d_in[15];
    const void* W1  = d_in[16];
    const void* b1  = d_in[17];
    const void* W2  = d_in[18];
    const void* b2  = d_in[19];

    char* ws = (char*)d_ws;
    ushort_t* Qb  = (ushort_t*)(ws + 0);
    ushort_t* Kb  = (ushort_t*)(ws + 8388608);
    ushort_t* Vb  = (ushort_t*)(ws + 16777216);
    ushort_t* Xp  = (ushort_t*)(ws + 33554432);
    ushort_t* Gs  = (ushort_t*)(ws + 8388608);
    ushort_t* Wqt = (ushort_t*)(ws + 41943040);
    ushort_t* W1t = (ushort_t*)(ws + 43515904);
    ushort_t* W2t = (ushort_t*)(ws + 45613056);
    int*      flg = (int*)(ws + 47710208);

    pre_kernel<<<dim3(4864), dim3(256), 0, stream>>>(
        x, Wq, Wk, Wv, W1, W2, Xp, Wqt, W1t, W2t, flg);

    const float scale = 0.125f;  // 1/sqrt(64)
    gemm8p_kernel<3><<<dim3(32, 6), dim3(512), 0, stream>>>(
        Xp, Wqt, bq, bk, bv, Qb, 8192, 1536, 512, scale, flg);

    attn_mfma_kernel<<<dim3(1024), dim3(256), 0, stream>>>(Qb, Kb, Vb);

    ln_kernel<<<dim3(8190), dim3(256), 0, stream>>>(Xp, Qb, lng, lnb, flg);

    gemm8p_kernel<1><<<dim3(32, 8), dim3(512), 0, stream>>>(
        Qb, W1t, b1, b1, b1, Gs, 8192, 2048, 512, 1.0f, flg);
    gemm_splitk_kernel<<<dim3(256), dim3(512), 0, stream>>>(
        Gs, W2t, b2, d_out, Qb, flg);
}